// Round 8
// baseline (199.205 us; speedup 1.0000x reference)
//
#include <hip/hip_runtime.h>
#include <math.h>

#define NB 4
#define NP 4096   // src points per batch
#define MP 4096   // tgt points per batch

typedef __bf16 bf16x8 __attribute__((ext_vector_type(8)));
typedef float  f32x16 __attribute__((ext_vector_type(16)));

// round-to-nearest-even fp32 -> bf16 (as raw u16)
static __device__ __forceinline__ unsigned short bh(float f) {
    unsigned u = __float_as_uint(f);
    unsigned r = (u + 0x7FFFu + ((u >> 16) & 1u)) >> 16;
    return (unsigned short)r;
}
static __device__ __forceinline__ float hf(unsigned short h) {
    return __uint_as_float(((unsigned)h) << 16);
}

// fast hw approximations (v_rcp_f32 / v_rsq_f32 / v_sqrt_f32, ~1 ulp) —
// proven benign in R7 (absmax unchanged at 0.015625).
static __device__ __forceinline__ float frcp(float x)  { return __builtin_amdgcn_rcpf(x); }
static __device__ __forceinline__ float frsq(float x)  { return __builtin_amdgcn_rsqf(x); }
static __device__ __forceinline__ float fsqrt(float x) { return __builtin_amdgcn_sqrtf(x); }

// ---------------------------------------------------------------------------
// fp32 3x3 Kabsch from the 15 reduced sums (R7's fast-math version).
// ---------------------------------------------------------------------------
__device__ __forceinline__ void kabsch_f32(const float* s, float* RtL) {
    const float invN = 1.0f / (float)NP;
    float cs[3] = { s[0] * invN, s[1] * invN, s[2] * invN };
    float ct[3] = { s[3] * invN, s[4] * invN, s[5] * invN };
    float H[3][3];
    for (int d = 0; d < 3; ++d)
        for (int e = 0; e < 3; ++e)
            H[d][e] = s[6 + d * 3 + e] * invN - cs[d] * ct[e];

    float A[3][3];
    for (int i = 0; i < 3; ++i)
        for (int j = 0; j < 3; ++j)
            A[i][j] = H[0][i] * H[0][j] + H[1][i] * H[1][j] + H[2][i] * H[2][j];

    float V[3][3] = {{1, 0, 0}, {0, 1, 0}, {0, 0, 1}};
    for (int sweep = 0; sweep < 6; ++sweep) {
        float off = A[0][1] * A[0][1] + A[0][2] * A[0][2] + A[1][2] * A[1][2];
        if (off < 1e-16f) break;
        for (int pi = 0; pi < 3; ++pi) {
            const int p = (pi == 2) ? 1 : 0;
            const int q = (pi == 0) ? 1 : 2;
            float apq = A[p][q];
            if (fabsf(apq) < 1e-30f) continue;
            float theta = (A[q][q] - A[p][p]) * 0.5f * frcp(apq);
            float t = frcp(fabsf(theta) + fsqrt(1.0f + theta * theta));
            if (theta < 0.0f) t = -t;
            float cth = frsq(1.0f + t * t);
            float sth = t * cth;
            float App = A[p][p], Aqq = A[q][q];
            A[p][p] = App - t * apq;
            A[q][q] = Aqq + t * apq;
            A[p][q] = A[q][p] = 0.0f;
            const int r = 3 - p - q;
            float Apr = A[p][r], Aqr = A[q][r];
            A[p][r] = A[r][p] = cth * Apr - sth * Aqr;
            A[q][r] = A[r][q] = sth * Apr + cth * Aqr;
            for (int i = 0; i < 3; ++i) {
                float Vip = V[i][p], Viq = V[i][q];
                V[i][p] = cth * Vip - sth * Viq;
                V[i][q] = sth * Vip + cth * Viq;
            }
        }
    }
    float lam[3] = { A[0][0], A[1][1], A[2][2] };
    for (int i = 0; i < 2; ++i)
        for (int j = i + 1; j < 3; ++j)
            if (lam[j] > lam[i]) {
                float tl = lam[i]; lam[i] = lam[j]; lam[j] = tl;
                for (int k = 0; k < 3; ++k) {
                    float tv = V[k][i]; V[k][i] = V[k][j]; V[k][j] = tv;
                }
            }

    float U[3][3];
    for (int k = 0; k < 3; ++k) {
        float w0 = H[0][0] * V[0][k] + H[0][1] * V[1][k] + H[0][2] * V[2][k];
        float w1 = H[1][0] * V[0][k] + H[1][1] * V[1][k] + H[1][2] * V[2][k];
        float w2 = H[2][0] * V[0][k] + H[2][1] * V[1][k] + H[2][2] * V[2][k];
        float d2 = w0 * w0 + w1 * w1 + w2 * w2;
        if (d2 > 1e-40f) {
            float inr = frsq(d2);
            U[0][k] = w0 * inr; U[1][k] = w1 * inr; U[2][k] = w2 * inr;
        } else {
            U[0][k] = U[1][0] * U[2][1] - U[2][0] * U[1][1];
            U[1][k] = U[2][0] * U[0][1] - U[0][0] * U[2][1];
            U[2][k] = U[0][0] * U[1][1] - U[1][0] * U[0][1];
        }
    }

    float detH = H[0][0] * (H[1][1] * H[2][2] - H[1][2] * H[2][1])
               - H[0][1] * (H[1][0] * H[2][2] - H[1][2] * H[2][0])
               + H[0][2] * (H[1][0] * H[2][1] - H[1][1] * H[2][0]);
    float sgn = (detH < 0.0f) ? -1.0f : 1.0f;

    float R[3][3];
    for (int i = 0; i < 3; ++i)
        for (int j = 0; j < 3; ++j)
            R[i][j] = V[i][0] * U[j][0] + V[i][1] * U[j][1] + sgn * V[i][2] * U[j][2];
    float tv[3];
    for (int i = 0; i < 3; ++i)
        tv[i] = ct[i] - (R[i][0] * cs[0] + R[i][1] * cs[1] + R[i][2] * cs[2]);

    for (int i = 0; i < 3; ++i)
        for (int j = 0; j < 3; ++j)
            RtL[i * 3 + j] = R[i][j];
    for (int i = 0; i < 3; ++i) RtL[9 + i] = tv[i];
}

// ---------------------------------------------------------------------------
// Init: build tgt4 (x,y,z,|t|^2) for gathers AND the pre-packed bf16 hi/lo
// B-fragments for mfma_f32_32x32x16_bf16.
// ---------------------------------------------------------------------------
__global__ __launch_bounds__(256) void icp_init(const float* __restrict__ tgt,
                                                float4* __restrict__ tgt4,
                                                uint4* __restrict__ Bbuf) {
    const int t    = blockIdx.x * 256 + threadIdx.x;   // 0..32767
    const int b    = t >> 13;
    const int rem  = t & 8191;
    const int tile = rem >> 6;        // 0..127 (32 tgt pts each)
    const int lane = rem & 63;
    const int n    = lane & 31;
    const int h    = lane >> 5;
    const int gt   = b * MP + tile * 32 + n;

    float x = tgt[gt * 3 + 0];
    float y = tgt[gt * 3 + 1];
    float z = tgt[gt * 3 + 2];
    float wv = x * x + y * y + z * z;

    unsigned short xh = bh(x), xl = bh(x - hf(xh));
    unsigned short yh = bh(y), yl = bh(y - hf(yh));
    unsigned short zh = bh(z), zl = bh(z - hf(zh));
    unsigned short wh = bh(wv), wl = bh(wv - hf(wh));
    const unsigned short ONE = 0x3F80;

    unsigned short s0, s1, s2, s3, s4, s5, s6, s7;
    if (h == 0) { s0 = xh; s1 = xh; s2 = xl; s3 = xl;
                  s4 = yh; s5 = yh; s6 = yl; s7 = yl; }
    else        { s0 = zh; s1 = zh; s2 = zl; s3 = zl;
                  s4 = wh; s5 = wl; s6 = ONE; s7 = ONE; }
    uint4 u;
    u.x = (unsigned)s0 | ((unsigned)s1 << 16);
    u.y = (unsigned)s2 | ((unsigned)s3 << 16);
    u.z = (unsigned)s4 | ((unsigned)s5 << 16);
    u.w = (unsigned)s6 | ((unsigned)s7 << 16);
    Bbuf[t] = u;

    if (h == 0) tgt4[gt] = make_float4(x, y, z, wv);
}

// ---------------------------------------------------------------------------
// One ICP iteration per dispatch. NEW GRID: 512 blocks x 512 threads
// (2 blocks/CU) so that while one block's wave 0 runs its serial
// solve/combine phases, the co-resident block's 8 waves keep the SIMDs fed.
// Block = (batch b = blk>>7, src-group g = blk&127 of 32 points). Wave w
// owns tgt-range w (16 tiles x 32 tgt). Lane's own point IS its A-fragment
// column (m = l&31) -> no shfl broadcast needed. 128 partials per batch.
// ---------------------------------------------------------------------------
__global__ __launch_bounds__(512, 4) void icp_scan(
        const float* __restrict__ src,
        const float4* __restrict__ tgt4,
        const uint4* __restrict__ Bbuf,
        float* __restrict__ S,            // [NB*NP*3] transformed points
        const float* __restrict__ pprev,  // [512][16] prev partials
        float* __restrict__ pout,         // [512][16] this iter's partials
        int first) {
    __shared__ unsigned CK[256];          // [tr(8)][src(32)]
    __shared__ float RtL[12];

    const int blk = blockIdx.x;           // 0..511
    const int b   = blk >> 7;             // batch
    const int g   = blk & 127;            // src-group (32 points)
    const int tid = threadIdx.x;          // 0..511
    const int w   = tid >> 6;             // 0..7 = tgt range
    const int l   = tid & 63;
    const int m   = l & 31;               // src row within group
    const int h   = l >> 5;
    const int gsrc = b * NP + g * 32 + m; // lanes 32-63 duplicate 0-31

    // ---- issue independent loads FIRST so L2 latency hides under the solve
    const uint4* Bw = Bbuf + (b * 128 + w * 16) * 64;
    uint4 fb[4];
    fb[0] = Bw[l];
    fb[1] = Bw[64 + l];
    fb[2] = Bw[128 + l];
    fb[3] = Bw[192 + l];

    const float* P = first ? src : S;
    float x0 = P[gsrc * 3 + 0];
    float y0 = P[gsrc * 3 + 1];
    float z0 = P[gsrc * 3 + 2];

    // ---- prologue: wave 0 redundantly solves prev iteration's (R,t) ----
    if (w == 0) {
        if (first) {
            if (l < 12) RtL[l] = (l == 0 || l == 4 || l == 8) ? 1.0f : 0.0f;
        } else {
            // 128 partials per batch: lane l folds partials l and l+64
            const float4* rp0 = (const float4*)(pprev + (b * 128 + l) * 16);
            const float4* rp1 = (const float4*)(pprev + (b * 128 + 64 + l) * 16);
            float4 a0 = rp0[0], a1 = rp0[1], a2 = rp0[2], a3 = rp0[3];
            float4 c0 = rp1[0], c1 = rp1[1], c2 = rp1[2], c3 = rp1[3];
            float sm[15] = { a0.x + c0.x, a0.y + c0.y, a0.z + c0.z, a0.w + c0.w,
                             a1.x + c1.x, a1.y + c1.y, a1.z + c1.z, a1.w + c1.w,
                             a2.x + c2.x, a2.y + c2.y, a2.z + c2.z, a2.w + c2.w,
                             a3.x + c3.x, a3.y + c3.y, a3.z + c3.z };
            #pragma unroll
            for (int k = 0; k < 15; ++k) {
                float v = sm[k];
                v += __shfl_down(v, 32);
                v += __shfl_down(v, 16);
                v += __shfl_down(v, 8);
                v += __shfl_down(v, 4);
                v += __shfl_down(v, 2);
                v += __shfl_down(v, 1);
                sm[k] = v;
            }
            if (l == 0) kabsch_f32(sm, RtL);
        }
    }
    __syncthreads();

    // ---- transform own point; wave 1 (h==0 lanes) persists it ----
    float px = x0 * RtL[0] + y0 * RtL[3] + z0 * RtL[6] + RtL[9];
    float py = x0 * RtL[1] + y0 * RtL[4] + z0 * RtL[7] + RtL[10];
    float pz = x0 * RtL[2] + y0 * RtL[5] + z0 * RtL[8] + RtL[11];
    if (w == 1 && h == 0) {
        S[gsrc * 3 + 0] = px;
        S[gsrc * 3 + 1] = py;
        S[gsrc * 3 + 2] = pz;
    }

    // ---- build A-fragment: A[m][k=(l>>5)*8+j] directly from own point ----
    union { unsigned short s[8]; bf16x8 v; } Af;
    {
        float ax = -2.0f * px, ay = -2.0f * py, az = -2.0f * pz;
        float qv = px * px + py * py + pz * pz + 1.0f;
        unsigned short axh = bh(ax), axl = bh(ax - hf(axh));
        unsigned short ayh = bh(ay), ayl = bh(ay - hf(ayh));
        unsigned short azh = bh(az), azl = bh(az - hf(azh));
        unsigned short qh  = bh(qv), ql  = bh(qv - hf(qh));
        const unsigned short ONE = 0x3F80;
        if (h == 0) {
            Af.s[0] = axh; Af.s[1] = axl; Af.s[2] = axh; Af.s[3] = axl;
            Af.s[4] = ayh; Af.s[5] = ayl; Af.s[6] = ayh; Af.s[7] = ayl;
        } else {
            Af.s[0] = azh; Af.s[1] = azl; Af.s[2] = azh; Af.s[3] = azl;
            Af.s[4] = ONE; Af.s[5] = ONE; Af.s[6] = qh;  Af.s[7] = ql;
        }
    }

    // ---- 16-tile scan on the MFMA pipe ----
    f32x16 zero;
    #pragma unroll
    for (int i = 0; i < 16; ++i) zero[i] = 0.0f;

    float best[16];
    #pragma unroll
    for (int r = 0; r < 16; ++r) best[r] = __uint_as_float(0x7F7FFFFFu);

    #pragma unroll
    for (int t = 0; t < 16; ++t) {
        bf16x8 Bf = __builtin_bit_cast(bf16x8, fb[t & 3]);
        if (t < 12) fb[t & 3] = Bw[(t + 4) * 64 + l];
        f32x16 d16 = __builtin_amdgcn_mfma_f32_32x32x16_bf16(Af.v, Bf, zero,
                                                             0, 0, 0);
        const unsigned idxk = (unsigned)((w * 16 + t) * 32 + m);
        #pragma unroll
        for (int r = 0; r < 16; ++r) {
            float key = __uint_as_float(
                (__float_as_uint(d16[r]) & 0xFFFFF000u) | idxk);
            best[r] = fminf(best[r], key);
        }
    }

    // ---- reduce across the 32 columns (lanes within each half-wave) ----
    #pragma unroll
    for (int r = 0; r < 16; ++r) {
        float v = best[r];
        v = fminf(v, __shfl_xor(v, 1));
        v = fminf(v, __shfl_xor(v, 2));
        v = fminf(v, __shfl_xor(v, 4));
        v = fminf(v, __shfl_xor(v, 8));
        v = fminf(v, __shfl_xor(v, 16));
        best[r] = v;
    }
    if (m == 0) {
        #pragma unroll
        for (int r = 0; r < 16; ++r) {
            const int row = (r & 3) + 8 * (r >> 2) + 4 * h;  // 0..31
            CK[w * 32 + row] = __float_as_uint(best[r]);
        }
    }
    __syncthreads();

    // ---- wave 0: combine 8 tgt-ranges, gather match, 15-sum ----
    if (w == 0) {
        float v[15];
        #pragma unroll
        for (int k = 0; k < 15; ++k) v[k] = 0.0f;
        if (l < 32) {
            unsigned kb = CK[l];
            #pragma unroll
            for (int k = 1; k < 8; ++k) {
                unsigned kk = CK[k * 32 + l];
                kb = kk < kb ? kk : kb;
            }
            const int idx = kb & 0xFFF;
            float4 mt = tgt4[b * MP + idx];
            const float tx = mt.x, ty = mt.y, tz = mt.z;
            v[0]  = px;      v[1]  = py;      v[2]  = pz;
            v[3]  = tx;      v[4]  = ty;      v[5]  = tz;
            v[6]  = px * tx; v[7]  = px * ty; v[8]  = px * tz;
            v[9]  = py * tx; v[10] = py * ty; v[11] = py * tz;
            v[12] = pz * tx; v[13] = pz * ty; v[14] = pz * tz;
        }
        #pragma unroll
        for (int k = 0; k < 15; ++k) {
            float s = v[k];
            s += __shfl_down(s, 32);
            s += __shfl_down(s, 16);
            s += __shfl_down(s, 8);
            s += __shfl_down(s, 4);
            s += __shfl_down(s, 2);
            s += __shfl_down(s, 1);
            v[k] = s;
        }
        if (l == 0) {
            float* pp = pout + blk * 16;
            #pragma unroll
            for (int k = 0; k < 15; ++k) pp[k] = v[k];
        }
    }
}

// Final: solve iteration-10's (R,t) (redundant per block), apply, write out.
// out layout: R [4,3,3] flat (36), t [4,3] flat (12), points [4,4096,3].
__global__ __launch_bounds__(256) void icp_final(
        const float* __restrict__ S,
        const float* __restrict__ plast,
        float* __restrict__ out) {
    __shared__ float RtL[12];
    const int bk  = blockIdx.x;
    const int tid = threadIdx.x;
    const int gid = bk * 256 + tid;               // 0..16383
    const int b   = gid >> 12;

    if (tid < 64) {
        const float4* rp0 = (const float4*)(plast + (b * 128 + tid) * 16);
        const float4* rp1 = (const float4*)(plast + (b * 128 + 64 + tid) * 16);
        float4 a0 = rp0[0], a1 = rp0[1], a2 = rp0[2], a3 = rp0[3];
        float4 c0 = rp1[0], c1 = rp1[1], c2 = rp1[2], c3 = rp1[3];
        float sm[15] = { a0.x + c0.x, a0.y + c0.y, a0.z + c0.z, a0.w + c0.w,
                         a1.x + c1.x, a1.y + c1.y, a1.z + c1.z, a1.w + c1.w,
                         a2.x + c2.x, a2.y + c2.y, a2.z + c2.z, a2.w + c2.w,
                         a3.x + c3.x, a3.y + c3.y, a3.z + c3.z };
        #pragma unroll
        for (int k = 0; k < 15; ++k) {
            float v = sm[k];
            v += __shfl_down(v, 32);
            v += __shfl_down(v, 16);
            v += __shfl_down(v, 8);
            v += __shfl_down(v, 4);
            v += __shfl_down(v, 2);
            v += __shfl_down(v, 1);
            sm[k] = v;
        }
        if (tid == 0) kabsch_f32(sm, RtL);
    }
    __syncthreads();

    float x = S[gid * 3 + 0];
    float y = S[gid * 3 + 1];
    float z = S[gid * 3 + 2];
    out[48 + gid * 3 + 0] = x * RtL[0] + y * RtL[3] + z * RtL[6] + RtL[9];
    out[48 + gid * 3 + 1] = x * RtL[1] + y * RtL[4] + z * RtL[7] + RtL[10];
    out[48 + gid * 3 + 2] = x * RtL[2] + y * RtL[5] + z * RtL[8] + RtL[11];
    if ((bk & 15) == 0) {
        if (tid < 9) out[b * 9 + tid] = RtL[tid];
        if (tid < 3) out[36 + b * 3 + tid] = RtL[9 + tid];
    }
}

extern "C" void kernel_launch(void* const* d_in, const int* in_sizes, int n_in,
                              void* d_out, int out_size, void* d_ws, size_t ws_size,
                              hipStream_t stream) {
    const float* src = (const float*)d_in[0];
    const float* tgt = (const float*)d_in[1];
    float* out = (float*)d_out;

    float* W     = (float*)d_ws;
    float4* tgt4 = (float4*)W;                       // 65536 floats
    uint4*  Bbuf = (uint4*)(W + 65536);              // 131072 floats (512 KB)
    float*  S    = W + 65536 + 131072;               // 49152 floats
    float*  pA   = S + 49152;                        // 8192 floats (512 x 16)
    float*  pB   = pA + 8192;                        // 8192 floats
    float* bufs[2] = { pA, pB };

    icp_init<<<128, 256, 0, stream>>>(tgt, tgt4, Bbuf);
    for (int k = 0; k < 10; ++k) {
        icp_scan<<<512, 512, 0, stream>>>(src, tgt4, Bbuf, S,
                                          bufs[(k + 1) & 1], bufs[k & 1],
                                          k == 0 ? 1 : 0);
    }
    icp_final<<<64, 256, 0, stream>>>(S, bufs[1], out);
}

// Round 9
// 160.818 us; speedup vs baseline: 1.2387x; 1.2387x over previous
//
#include <hip/hip_runtime.h>
#include <math.h>

#define NB 4
#define NP 4096   // src points per batch
#define MP 4096   // tgt points per batch

typedef __bf16 bf16x8 __attribute__((ext_vector_type(8)));
typedef float  f32x16 __attribute__((ext_vector_type(16)));

// round-to-nearest-even fp32 -> bf16 (as raw u16)
static __device__ __forceinline__ unsigned short bh(float f) {
    unsigned u = __float_as_uint(f);
    unsigned r = (u + 0x7FFFu + ((u >> 16) & 1u)) >> 16;
    return (unsigned short)r;
}
static __device__ __forceinline__ float hf(unsigned short h) {
    return __uint_as_float(((unsigned)h) << 16);
}

// fast hw approximations (v_rcp_f32 / v_rsq_f32 / v_sqrt_f32, ~1 ulp) —
// proven benign in R7 (absmax unchanged at 0.015625).
static __device__ __forceinline__ float frcp(float x)  { return __builtin_amdgcn_rcpf(x); }
static __device__ __forceinline__ float frsq(float x)  { return __builtin_amdgcn_rsqf(x); }
static __device__ __forceinline__ float fsqrt(float x) { return __builtin_amdgcn_sqrtf(x); }

// ---------------------------------------------------------------------------
// fp32 3x3 Kabsch from the 15 reduced sums (R7's fast-math version).
// ---------------------------------------------------------------------------
__device__ __forceinline__ void kabsch_f32(const float* s, float* RtL) {
    const float invN = 1.0f / (float)NP;
    float cs[3] = { s[0] * invN, s[1] * invN, s[2] * invN };
    float ct[3] = { s[3] * invN, s[4] * invN, s[5] * invN };
    float H[3][3];
    for (int d = 0; d < 3; ++d)
        for (int e = 0; e < 3; ++e)
            H[d][e] = s[6 + d * 3 + e] * invN - cs[d] * ct[e];

    float A[3][3];
    for (int i = 0; i < 3; ++i)
        for (int j = 0; j < 3; ++j)
            A[i][j] = H[0][i] * H[0][j] + H[1][i] * H[1][j] + H[2][i] * H[2][j];

    float V[3][3] = {{1, 0, 0}, {0, 1, 0}, {0, 0, 1}};
    for (int sweep = 0; sweep < 6; ++sweep) {
        float off = A[0][1] * A[0][1] + A[0][2] * A[0][2] + A[1][2] * A[1][2];
        if (off < 1e-16f) break;
        for (int pi = 0; pi < 3; ++pi) {
            const int p = (pi == 2) ? 1 : 0;
            const int q = (pi == 0) ? 1 : 2;
            float apq = A[p][q];
            if (fabsf(apq) < 1e-30f) continue;
            float theta = (A[q][q] - A[p][p]) * 0.5f * frcp(apq);
            float t = frcp(fabsf(theta) + fsqrt(1.0f + theta * theta));
            if (theta < 0.0f) t = -t;
            float cth = frsq(1.0f + t * t);
            float sth = t * cth;
            float App = A[p][p], Aqq = A[q][q];
            A[p][p] = App - t * apq;
            A[q][q] = Aqq + t * apq;
            A[p][q] = A[q][p] = 0.0f;
            const int r = 3 - p - q;
            float Apr = A[p][r], Aqr = A[q][r];
            A[p][r] = A[r][p] = cth * Apr - sth * Aqr;
            A[q][r] = A[r][q] = sth * Apr + cth * Aqr;
            for (int i = 0; i < 3; ++i) {
                float Vip = V[i][p], Viq = V[i][q];
                V[i][p] = cth * Vip - sth * Viq;
                V[i][q] = sth * Vip + cth * Viq;
            }
        }
    }
    float lam[3] = { A[0][0], A[1][1], A[2][2] };
    for (int i = 0; i < 2; ++i)
        for (int j = i + 1; j < 3; ++j)
            if (lam[j] > lam[i]) {
                float tl = lam[i]; lam[i] = lam[j]; lam[j] = tl;
                for (int k = 0; k < 3; ++k) {
                    float tv = V[k][i]; V[k][i] = V[k][j]; V[k][j] = tv;
                }
            }

    float U[3][3];
    for (int k = 0; k < 3; ++k) {
        float w0 = H[0][0] * V[0][k] + H[0][1] * V[1][k] + H[0][2] * V[2][k];
        float w1 = H[1][0] * V[0][k] + H[1][1] * V[1][k] + H[1][2] * V[2][k];
        float w2 = H[2][0] * V[0][k] + H[2][1] * V[1][k] + H[2][2] * V[2][k];
        float d2 = w0 * w0 + w1 * w1 + w2 * w2;
        if (d2 > 1e-40f) {
            float inr = frsq(d2);
            U[0][k] = w0 * inr; U[1][k] = w1 * inr; U[2][k] = w2 * inr;
        } else {
            U[0][k] = U[1][0] * U[2][1] - U[2][0] * U[1][1];
            U[1][k] = U[2][0] * U[0][1] - U[0][0] * U[2][1];
            U[2][k] = U[0][0] * U[1][1] - U[1][0] * U[0][1];
        }
    }

    float detH = H[0][0] * (H[1][1] * H[2][2] - H[1][2] * H[2][1])
               - H[0][1] * (H[1][0] * H[2][2] - H[1][2] * H[2][0])
               + H[0][2] * (H[1][0] * H[2][1] - H[1][1] * H[2][0]);
    float sgn = (detH < 0.0f) ? -1.0f : 1.0f;

    float R[3][3];
    for (int i = 0; i < 3; ++i)
        for (int j = 0; j < 3; ++j)
            R[i][j] = V[i][0] * U[j][0] + V[i][1] * U[j][1] + sgn * V[i][2] * U[j][2];
    float tv[3];
    for (int i = 0; i < 3; ++i)
        tv[i] = ct[i] - (R[i][0] * cs[0] + R[i][1] * cs[1] + R[i][2] * cs[2]);

    for (int i = 0; i < 3; ++i)
        for (int j = 0; j < 3; ++j)
            RtL[i * 3 + j] = R[i][j];
    for (int i = 0; i < 3; ++i) RtL[9 + i] = tv[i];
}

// ---------------------------------------------------------------------------
// Init: build tgt4 (x,y,z,|t|^2) for gathers AND the pre-packed bf16 hi/lo
// B-fragments for mfma_f32_32x32x16_bf16.
// ---------------------------------------------------------------------------
__global__ __launch_bounds__(256) void icp_init(const float* __restrict__ tgt,
                                                float4* __restrict__ tgt4,
                                                uint4* __restrict__ Bbuf) {
    const int t    = blockIdx.x * 256 + threadIdx.x;   // 0..32767
    const int b    = t >> 13;
    const int rem  = t & 8191;
    const int tile = rem >> 6;        // 0..127 (32 tgt pts each)
    const int lane = rem & 63;
    const int n    = lane & 31;
    const int h    = lane >> 5;
    const int gt   = b * MP + tile * 32 + n;

    float x = tgt[gt * 3 + 0];
    float y = tgt[gt * 3 + 1];
    float z = tgt[gt * 3 + 2];
    float wv = x * x + y * y + z * z;

    unsigned short xh = bh(x), xl = bh(x - hf(xh));
    unsigned short yh = bh(y), yl = bh(y - hf(yh));
    unsigned short zh = bh(z), zl = bh(z - hf(zh));
    unsigned short wh = bh(wv), wl = bh(wv - hf(wh));
    const unsigned short ONE = 0x3F80;

    unsigned short s0, s1, s2, s3, s4, s5, s6, s7;
    if (h == 0) { s0 = xh; s1 = xh; s2 = xl; s3 = xl;
                  s4 = yh; s5 = yh; s6 = yl; s7 = yl; }
    else        { s0 = zh; s1 = zh; s2 = zl; s3 = zl;
                  s4 = wh; s5 = wl; s6 = ONE; s7 = ONE; }
    uint4 u;
    u.x = (unsigned)s0 | ((unsigned)s1 << 16);
    u.y = (unsigned)s2 | ((unsigned)s3 << 16);
    u.z = (unsigned)s4 | ((unsigned)s5 << 16);
    u.w = (unsigned)s6 | ((unsigned)s7 << 16);
    Bbuf[t] = u;

    if (h == 0) tgt4[gt] = make_float4(x, y, z, wv);
}

// ---------------------------------------------------------------------------
// One ICP iteration per dispatch. 256 blocks (batch b = blk>>6, src-group
// g = blk&63; lane l owns src point l), 1024 threads = 16 waves. R7 structure;
// NEW: the 32-column min-reduce is a 5-step FOLD (16 shuffles/thread, was 80)
// that halves the live row-set each step. After folding on lane bits
// {16,8,4,2}, lane lb holds row rf=(lb>>1)&15 reduced over all 32 columns
// (xor-1 pair duplicates; even lane writes CK). Keys embed their own column
// index so the winning key is bit-identical to the old reduce.
// ---------------------------------------------------------------------------
__global__ __launch_bounds__(1024, 4) void icp_scan(
        const float* __restrict__ src,
        const float4* __restrict__ tgt4,
        const uint4* __restrict__ Bbuf,
        float* __restrict__ S,            // [NB*NP*3] transformed points
        const float* __restrict__ pprev,  // [256][16] prev partials
        float* __restrict__ pout,         // [256][16] this iter's partials
        int first) {
    __shared__ unsigned CK[512];          // [tr(8)][src(64)]
    __shared__ float RtL[12];

    const int blk = blockIdx.x;
    const int b   = blk >> 6;
    const int g   = blk & 63;
    const int tid = threadIdx.x;
    const int w   = tid >> 6;
    const int l   = tid & 63;
    const int ts  = w & 1;
    const int tr  = w >> 1;
    const int gsrc = b * NP + g * 64 + l;

    // ---- issue independent loads FIRST so L2 latency hides under the solve
    const uint4* Bw = Bbuf + (b * 128 + tr * 16) * 64;
    uint4 fb[4];
    fb[0] = Bw[l];
    fb[1] = Bw[64 + l];
    fb[2] = Bw[128 + l];
    fb[3] = Bw[192 + l];

    const float* P = first ? src : S;
    float x0 = P[gsrc * 3 + 0];
    float y0 = P[gsrc * 3 + 1];
    float z0 = P[gsrc * 3 + 2];

    // ---- prologue: wave 0 redundantly solves prev iteration's (R,t) ----
    if (w == 0) {
        if (first) {
            if (l < 12) RtL[l] = (l == 0 || l == 4 || l == 8) ? 1.0f : 0.0f;
        } else {
            const float4* rp = (const float4*)(pprev + (b * 64 + l) * 16);
            float4 r0 = rp[0], r1 = rp[1], r2 = rp[2], r3 = rp[3];
            float sm[15] = { r0.x, r0.y, r0.z, r0.w, r1.x, r1.y, r1.z, r1.w,
                             r2.x, r2.y, r2.z, r2.w, r3.x, r3.y, r3.z };
            #pragma unroll
            for (int k = 0; k < 15; ++k) {
                float v = sm[k];
                v += __shfl_down(v, 32);
                v += __shfl_down(v, 16);
                v += __shfl_down(v, 8);
                v += __shfl_down(v, 4);
                v += __shfl_down(v, 2);
                v += __shfl_down(v, 1);
                sm[k] = v;
            }
            if (l == 0) kabsch_f32(sm, RtL);
        }
    }
    __syncthreads();

    // ---- transform own point; wave 1 persists it for the next iteration ----
    float px = x0 * RtL[0] + y0 * RtL[3] + z0 * RtL[6] + RtL[9];
    float py = x0 * RtL[1] + y0 * RtL[4] + z0 * RtL[7] + RtL[10];
    float pz = x0 * RtL[2] + y0 * RtL[5] + z0 * RtL[8] + RtL[11];
    if (w == 1) {
        S[gsrc * 3 + 0] = px;
        S[gsrc * 3 + 1] = py;
        S[gsrc * 3 + 2] = pz;
    }

    // ---- build A-fragment: A[m=lane&31][k=(lane>>5)*8+j] ----
    const int h = l >> 5;
    union { unsigned short s[8]; bf16x8 v; } Af;
    {
        const int j3 = ts * 32 + (l & 31);     // src point this lane's m maps to
        float pxj = __shfl(px, j3);
        float pyj = __shfl(py, j3);
        float pzj = __shfl(pz, j3);
        float ax = -2.0f * pxj, ay = -2.0f * pyj, az = -2.0f * pzj;
        float qv = pxj * pxj + pyj * pyj + pzj * pzj + 1.0f;
        unsigned short axh = bh(ax), axl = bh(ax - hf(axh));
        unsigned short ayh = bh(ay), ayl = bh(ay - hf(ayh));
        unsigned short azh = bh(az), azl = bh(az - hf(azh));
        unsigned short qh  = bh(qv), ql  = bh(qv - hf(qh));
        const unsigned short ONE = 0x3F80;
        if (h == 0) {
            Af.s[0] = axh; Af.s[1] = axl; Af.s[2] = axh; Af.s[3] = axl;
            Af.s[4] = ayh; Af.s[5] = ayl; Af.s[6] = ayh; Af.s[7] = ayl;
        } else {
            Af.s[0] = azh; Af.s[1] = azl; Af.s[2] = azh; Af.s[3] = azl;
            Af.s[4] = ONE; Af.s[5] = ONE; Af.s[6] = qh;  Af.s[7] = ql;
        }
    }

    // ---- 16-tile scan on the MFMA pipe ----
    f32x16 zero;
    #pragma unroll
    for (int i = 0; i < 16; ++i) zero[i] = 0.0f;

    float best[16];
    #pragma unroll
    for (int r = 0; r < 16; ++r) best[r] = __uint_as_float(0x7F7FFFFFu);

    const int col = l & 31;

    #pragma unroll
    for (int t = 0; t < 16; ++t) {
        bf16x8 Bf = __builtin_bit_cast(bf16x8, fb[t & 3]);
        if (t < 12) fb[t & 3] = Bw[(t + 4) * 64 + l];
        f32x16 d16 = __builtin_amdgcn_mfma_f32_32x32x16_bf16(Af.v, Bf, zero,
                                                             0, 0, 0);
        const unsigned idxk = (unsigned)((tr * 16 + t) * 32 + col);
        #pragma unroll
        for (int r = 0; r < 16; ++r) {
            float key = __uint_as_float(
                (__float_as_uint(d16[r]) & 0xFFFFF000u) | idxk);
            best[r] = fminf(best[r], key);
        }
    }

    // ---- FOLD-reduce across the 32 columns: 16 shuffles (was 80) ----
    const int lb = l & 31;
    float f8[8];
    {
        const bool hi = (lb & 16) != 0;
        #pragma unroll
        for (int r = 0; r < 8; ++r) {
            float send = hi ? best[r] : best[r + 8];
            float recv = __shfl_xor(send, 16);
            float keep = hi ? best[r + 8] : best[r];
            f8[r] = fminf(keep, recv);
        }
    }
    float f4[4];
    {
        const bool hi = (lb & 8) != 0;
        #pragma unroll
        for (int r = 0; r < 4; ++r) {
            float send = hi ? f8[r] : f8[r + 4];
            float recv = __shfl_xor(send, 8);
            float keep = hi ? f8[r + 4] : f8[r];
            f4[r] = fminf(keep, recv);
        }
    }
    float f2[2];
    {
        const bool hi = (lb & 4) != 0;
        #pragma unroll
        for (int r = 0; r < 2; ++r) {
            float send = hi ? f4[r] : f4[r + 2];
            float recv = __shfl_xor(send, 4);
            float keep = hi ? f4[r + 2] : f4[r];
            f2[r] = fminf(keep, recv);
        }
    }
    float f1;
    {
        const bool hi = (lb & 2) != 0;
        float send = hi ? f2[0] : f2[1];
        float recv = __shfl_xor(send, 2);
        float keep = hi ? f2[1] : f2[0];
        f1 = fminf(keep, recv);
    }
    f1 = fminf(f1, __shfl_xor(f1, 1));
    {
        const int rf  = (lb >> 1) & 15;                   // folded row index
        const int row = (rf & 3) + 8 * (rf >> 2) + 4 * h; // same map as before
        if ((l & 1) == 0) CK[tr * 64 + ts * 32 + row] = __float_as_uint(f1);
    }
    __syncthreads();

    // ---- wave 0: combine 8 tgt-ranges, gather match, 15-sum ----
    if (w == 0) {
        unsigned kb = CK[l];
        #pragma unroll
        for (int k = 1; k < 8; ++k) {
            unsigned kk = CK[k * 64 + l];
            kb = kk < kb ? kk : kb;
        }
        const int idx = kb & 0xFFF;
        float4 mt = tgt4[b * MP + idx];
        const float tx = mt.x, ty = mt.y, tz = mt.z;

        float v[15];
        v[0]  = px;      v[1]  = py;      v[2]  = pz;
        v[3]  = tx;      v[4]  = ty;      v[5]  = tz;
        v[6]  = px * tx; v[7]  = px * ty; v[8]  = px * tz;
        v[9]  = py * tx; v[10] = py * ty; v[11] = py * tz;
        v[12] = pz * tx; v[13] = pz * ty; v[14] = pz * tz;
        #pragma unroll
        for (int k = 0; k < 15; ++k) {
            float s = v[k];
            s += __shfl_down(s, 32);
            s += __shfl_down(s, 16);
            s += __shfl_down(s, 8);
            s += __shfl_down(s, 4);
            s += __shfl_down(s, 2);
            s += __shfl_down(s, 1);
            v[k] = s;
        }
        if (l == 0) {
            float* pp = pout + blk * 16;
            #pragma unroll
            for (int k = 0; k < 15; ++k) pp[k] = v[k];
        }
    }
}

// Final: solve iteration-10's (R,t) (redundant per block), apply, write out.
// out layout: R [4,3,3] flat (36), t [4,3] flat (12), points [4,4096,3].
__global__ __launch_bounds__(256) void icp_final(
        const float* __restrict__ S,
        const float* __restrict__ plast,
        float* __restrict__ out) {
    __shared__ float RtL[12];
    const int bk  = blockIdx.x;
    const int tid = threadIdx.x;
    const int gid = bk * 256 + tid;               // 0..16383
    const int b   = gid >> 12;

    if (tid < 64) {
        const float4* rp = (const float4*)(plast + (b * 64 + tid) * 16);
        float4 r0 = rp[0], r1 = rp[1], r2 = rp[2], r3 = rp[3];
        float sm[15] = { r0.x, r0.y, r0.z, r0.w, r1.x, r1.y, r1.z, r1.w,
                         r2.x, r2.y, r2.z, r2.w, r3.x, r3.y, r3.z };
        #pragma unroll
        for (int k = 0; k < 15; ++k) {
            float v = sm[k];
            v += __shfl_down(v, 32);
            v += __shfl_down(v, 16);
            v += __shfl_down(v, 8);
            v += __shfl_down(v, 4);
            v += __shfl_down(v, 2);
            v += __shfl_down(v, 1);
            sm[k] = v;
        }
        if (tid == 0) kabsch_f32(sm, RtL);
    }
    __syncthreads();

    float x = S[gid * 3 + 0];
    float y = S[gid * 3 + 1];
    float z = S[gid * 3 + 2];
    out[48 + gid * 3 + 0] = x * RtL[0] + y * RtL[3] + z * RtL[6] + RtL[9];
    out[48 + gid * 3 + 1] = x * RtL[1] + y * RtL[4] + z * RtL[7] + RtL[10];
    out[48 + gid * 3 + 2] = x * RtL[2] + y * RtL[5] + z * RtL[8] + RtL[11];
    if ((bk & 15) == 0) {
        if (tid < 9) out[b * 9 + tid] = RtL[tid];
        if (tid < 3) out[36 + b * 3 + tid] = RtL[9 + tid];
    }
}

extern "C" void kernel_launch(void* const* d_in, const int* in_sizes, int n_in,
                              void* d_out, int out_size, void* d_ws, size_t ws_size,
                              hipStream_t stream) {
    const float* src = (const float*)d_in[0];
    const float* tgt = (const float*)d_in[1];
    float* out = (float*)d_out;

    float* W     = (float*)d_ws;
    float4* tgt4 = (float4*)W;                       // 65536 floats
    uint4*  Bbuf = (uint4*)(W + 65536);              // 131072 floats (512 KB)
    float*  S    = W + 65536 + 131072;               // 49152 floats
    float*  pA   = S + 49152;                        // 4096 floats
    float*  pB   = pA + 4096;                        // 4096 floats
    float* bufs[2] = { pA, pB };

    icp_init<<<128, 256, 0, stream>>>(tgt, tgt4, Bbuf);
    for (int k = 0; k < 10; ++k) {
        icp_scan<<<256, 1024, 0, stream>>>(src, tgt4, Bbuf, S,
                                           bufs[(k + 1) & 1], bufs[k & 1],
                                           k == 0 ? 1 : 0);
    }
    icp_final<<<64, 256, 0, stream>>>(S, bufs[1], out);
}